// Round 1
// baseline (244.135 us; speedup 1.0000x reference)
//
#include <hip/hip_runtime.h>

#define FARD 1e10f
#define EPSV 1e-10f

// One ray per 16-lane segment; each lane owns 4 consecutive samples.
// All global loads are float4 (16B/lane), fully coalesced.
__global__ __launch_bounds__(256) void nerf_render_kernel(
    const float* __restrict__ sigmas,   // (N, 64)
    const float* __restrict__ rgbs,     // (N, 64, 3)
    const float* __restrict__ z_vals,   // (N, 64)
    float* __restrict__ out,            // [rgb 3N | depth N | accum N]
    int n_rays)
{
    const int tid = blockIdx.x * blockDim.x + threadIdx.x;
    const int ray = tid >> 4;
    if (ray >= n_rays) return;
    const int l = threadIdx.x & 15;     // lane within 16-lane segment

    // ---- loads (all 16B vector loads) ----
    const float4 sg = *reinterpret_cast<const float4*>(sigmas + (size_t)ray * 64 + l * 4);
    const float4 zv = *reinterpret_cast<const float4*>(z_vals + (size_t)ray * 64 + l * 4);
    const float* rp = rgbs + (size_t)ray * 192 + l * 12;
    const float4 c0 = *reinterpret_cast<const float4*>(rp);      // r0 g0 b0 r1
    const float4 c1 = *reinterpret_cast<const float4*>(rp + 4);  // g1 b1 r2 g2
    const float4 c2 = *reinterpret_cast<const float4*>(rp + 8);  // b2 r3 g3 b3

    // z of next lane's first sample (sample 4l+4); unused at l==15
    const float zn = __shfl_down(zv.x, 1, 16);

    const float d0 = zv.y - zv.x;
    const float d1 = zv.z - zv.y;
    const float d2 = zv.w - zv.z;
    const float d3 = (l == 15) ? FARD : (zn - zv.w);

    // e = exp(-relu(sigma)*delta); trans = e + eps (== 1 - alpha + eps exactly)
    const float e0 = __expf(-fmaxf(sg.x, 0.f) * d0);
    const float e1 = __expf(-fmaxf(sg.y, 0.f) * d1);
    const float e2 = __expf(-fmaxf(sg.z, 0.f) * d2);
    const float e3 = __expf(-fmaxf(sg.w, 0.f) * d3);

    const float a0 = 1.f - e0, a1 = 1.f - e1, a2 = 1.f - e2, a3 = 1.f - e3;
    const float t0 = e0 + EPSV, t1 = e1 + EPSV, t2 = e2 + EPSV, t3 = e3 + EPSV;

    // ---- exclusive prefix product of trans across the 64 samples ----
    // lane-local product, then Hillis-Steele inclusive scan over 16 lanes
    float scan = t0 * t1 * t2 * t3;
    #pragma unroll
    for (int off = 1; off < 16; off <<= 1) {
        const float v = __shfl_up(scan, off, 16);
        if (l >= off) scan *= v;
    }
    float ex = __shfl_up(scan, 1, 16);   // exclusive: prod of trans before sample 4l
    if (l == 0) ex = 1.f;

    // ---- weights ----
    const float w0 = a0 * ex;
    float acc = ex * t0;
    const float w1 = a1 * acc; acc *= t1;
    const float w2 = a2 * acc; acc *= t2;
    const float w3 = a3 * acc;
    const float accT_62 = acc;           // at l==15: prod trans[0..62] = accum_trans[:,-1]

    // ---- per-lane partial sums ----
    float wsum = w0 + w1 + w2 + w3;
    float dsum = w0 * zv.x + w1 * zv.y + w2 * zv.z + w3 * zv.w;
    float rsum = w0 * c0.x + w1 * c0.w + w2 * c1.z + w3 * c2.y;
    float gsum = w0 * c0.y + w1 * c1.x + w2 * c1.w + w3 * c2.z;
    float bsum = w0 * c0.z + w1 * c1.y + w2 * c2.x + w3 * c2.w;

    // ---- butterfly reductions over the 16-lane segment ----
    #pragma unroll
    for (int off = 8; off >= 1; off >>= 1) {
        wsum += __shfl_xor(wsum, off, 16);
        dsum += __shfl_xor(dsum, off, 16);
        rsum += __shfl_xor(rsum, off, 16);
        gsum += __shfl_xor(gsum, off, 16);
        bsum += __shfl_xor(bsum, off, 16);
    }

    // ---- writes ----
    if (l == 0) {
        const float bg = 1.f - wsum;     // white background
        out[(size_t)ray * 3 + 0] = rsum + bg;
        out[(size_t)ray * 3 + 1] = gsum + bg;
        out[(size_t)ray * 3 + 2] = bsum + bg;
        out[(size_t)3 * n_rays + ray] = dsum;
    }
    if (l == 15) {
        out[(size_t)4 * n_rays + ray] = accT_62;
    }
}

extern "C" void kernel_launch(void* const* d_in, const int* in_sizes, int n_in,
                              void* d_out, int out_size, void* d_ws, size_t ws_size,
                              hipStream_t stream) {
    const float* sigmas = (const float*)d_in[0];
    const float* rgbs   = (const float*)d_in[1];
    const float* z_vals = (const float*)d_in[2];
    float* out = (float*)d_out;

    const int n_rays = in_sizes[0] / 64;
    const int threads = 256;
    const long long total_threads = (long long)n_rays * 16;
    const int blocks = (int)((total_threads + threads - 1) / threads);

    nerf_render_kernel<<<blocks, threads, 0, stream>>>(sigmas, rgbs, z_vals, out, n_rays);
}

// Round 2
// 240.767 us; speedup vs baseline: 1.0140x; 1.0140x over previous
//
#include <hip/hip_runtime.h>

#define FARD 1e10f
#define EPSV 1e-10f

// One ray per 8-lane segment; each lane owns 8 consecutive samples.
// All global loads are float4. Weights factored as w_k = ex * u_k so all
// reductions' partials are computed BEFORE the cross-lane scan.
__global__ __launch_bounds__(256) void nerf_render_kernel(
    const float* __restrict__ sigmas,   // (N, 64)
    const float* __restrict__ rgbs,     // (N, 64, 3)
    const float* __restrict__ z_vals,   // (N, 64)
    float* __restrict__ out,            // [rgb 3N | depth N | accum N]
    int n_rays)
{
    const int tid = blockIdx.x * blockDim.x + threadIdx.x;
    const int ray = tid >> 3;
    if (ray >= n_rays) return;
    const int l = threadIdx.x & 7;      // lane within 8-lane segment

    // ---- loads (10x float4 per lane, issued up front) ----
    const float4* sp = reinterpret_cast<const float4*>(sigmas + (size_t)ray * 64 + l * 8);
    const float4* zp = reinterpret_cast<const float4*>(z_vals + (size_t)ray * 64 + l * 8);
    const float4* cp = reinterpret_cast<const float4*>(rgbs   + (size_t)ray * 192 + l * 24);
    const float4 s0 = sp[0], s1 = sp[1];
    const float4 z0 = zp[0], z1 = zp[1];
    const float4 c0 = cp[0], c1 = cp[1], c2 = cp[2];
    const float4 c3 = cp[3], c4 = cp[4], c5 = cp[5];

    const float zz[8] = {z0.x, z0.y, z0.z, z0.w, z1.x, z1.y, z1.z, z1.w};
    const float sv[8] = {s0.x, s0.y, s0.z, s0.w, s1.x, s1.y, s1.z, s1.w};
    const float cc[24] = {c0.x, c0.y, c0.z, c0.w, c1.x, c1.y, c1.z, c1.w,
                          c2.x, c2.y, c2.z, c2.w, c3.x, c3.y, c3.z, c3.w,
                          c4.x, c4.y, c4.z, c4.w, c5.x, c5.y, c5.z, c5.w};

    // z of next lane's first sample (sample 8l+8); unused garbage at l==7
    const float zn = __shfl_down(z0.x, 1, 8);

    float d[8];
    #pragma unroll
    for (int k = 0; k < 7; ++k) d[k] = zz[k + 1] - zz[k];
    d[7] = (l == 7) ? FARD : (zn - zz[7]);

    // ---- lane-local pass: u_k = alpha_k * prod_{j<k} t_j ----
    // (t = e + eps == 1 - alpha + eps exactly, since e = exp(-relu(s)*d))
    float run = 1.f;     // running product of t within the lane
    float P6  = 1.f;     // product t0..t6 of this lane (valid use at l==7)
    float Wp = 0.f, Dp = 0.f, Rp = 0.f, Gp = 0.f, Bp = 0.f;
    #pragma unroll
    for (int k = 0; k < 8; ++k) {
        const float e = __expf(-fmaxf(sv[k], 0.f) * d[k]);
        const float u = (1.f - e) * run;
        if (k == 7) P6 = run;
        run *= (e + EPSV);
        Wp += u;
        Dp += u * zz[k];
        Rp += u * cc[3 * k + 0];
        Gp += u * cc[3 * k + 1];
        Bp += u * cc[3 * k + 2];
    }

    // ---- exclusive prefix product of lane products over 8 lanes ----
    float scan = run;
    #pragma unroll
    for (int off = 1; off < 8; off <<= 1) {
        const float v = __shfl_up(scan, off, 8);
        if (l >= off) scan *= v;
    }
    float ex = __shfl_up(scan, 1, 8);
    if (l == 0) ex = 1.f;

    // ---- scale partials, butterfly-reduce over the 8-lane segment ----
    float wsum = ex * Wp;
    float dsum = ex * Dp;
    float rsum = ex * Rp;
    float gsum = ex * Gp;
    float bsum = ex * Bp;
    #pragma unroll
    for (int off = 4; off >= 1; off >>= 1) {
        wsum += __shfl_xor(wsum, off, 8);
        dsum += __shfl_xor(dsum, off, 8);
        rsum += __shfl_xor(rsum, off, 8);
        gsum += __shfl_xor(gsum, off, 8);
        bsum += __shfl_xor(bsum, off, 8);
    }

    // ---- writes (all lanes hold the sums; spread for coalescing) ----
    const float bg = 1.f - wsum;
    if (l < 3) {
        const float v = (l == 0) ? rsum : ((l == 1) ? gsum : bsum);
        out[(size_t)ray * 3 + l] = v + bg;
    } else if (l == 3) {
        out[(size_t)3 * n_rays + ray] = dsum;
    } else if (l == 7) {
        out[(size_t)4 * n_rays + ray] = ex * P6;   // accum_trans[:, -1]
    }
}

extern "C" void kernel_launch(void* const* d_in, const int* in_sizes, int n_in,
                              void* d_out, int out_size, void* d_ws, size_t ws_size,
                              hipStream_t stream) {
    const float* sigmas = (const float*)d_in[0];
    const float* rgbs   = (const float*)d_in[1];
    const float* z_vals = (const float*)d_in[2];
    float* out = (float*)d_out;

    const int n_rays = in_sizes[0] / 64;
    const int threads = 256;
    const long long total_threads = (long long)n_rays * 8;
    const int blocks = (int)((total_threads + threads - 1) / threads);

    nerf_render_kernel<<<blocks, threads, 0, stream>>>(sigmas, rgbs, z_vals, out, n_rays);
}